// Round 7
// baseline (194.437 us; speedup 1.0000x reference)
//
#include <hip/hip_runtime.h>
#include <stdint.h>

// ---------------------------------------------------------------------------
// WeightGenerator_V4, round 6: Wd eliminated by reassociation.
//   out[e,p] = sum_i xc[g,i]*T_j[i,p] + U[j,p],  e = g*32+j
//   T_j[i,p] = sum_c wlinT[i][j*256+c]*Y[c,p]   (per patch, in-register/LDS)
//   U[j,p]   = sum_c b_lin[j*256+c]*Y[c,p]      (folded into k=16 MFMA slot)
//   k1a: grouped 3x3 conv -> xr. k1b: gate+dw+mul -> xc bf16; also emits
//   wlinT (16x8192 bf16) and blin bf16. k2: single fused kernel, 1024
//   half-patch blocks x 4 waves; Y B-frags hoisted to 32 VGPRs; j-loop is
//   barrier-free (wave-private LDS T double-buffer).
// ---------------------------------------------------------------------------

typedef __attribute__((ext_vector_type(8))) short short8;
typedef __attribute__((ext_vector_type(4))) float f32x4;

#define BN_EPS 1e-5f

__device__ __forceinline__ unsigned short f2bf(float f) {
  unsigned u = __float_as_uint(f);
  return (unsigned short)((u + 0x8000u) >> 16);
}
__device__ __forceinline__ unsigned pk2bf(float a, float b) {
  unsigned ua = __float_as_uint(a), ub = __float_as_uint(b);
  return ((ua + 0x8000u) >> 16) | ((ub + 0x8000u) & 0xFFFF0000u);
}

// =====================  k1a: grouped 3x3 conv -> xr  =====================
__global__ __launch_bounds__(256) void k1a_groupconv(
    const float* __restrict__ x, const float* __restrict__ w_cr,
    const float* __restrict__ b_cr, float* __restrict__ xr)
{
  __shared__ float xs[4][256];
  int b = blockIdx.x >> 6, cr = blockIdx.x & 63;
  int t = threadIdx.x;
  {
    int ch = t >> 6, off = (t & 63) * 4;
    float4 v = *(const float4*)(x + b * 65536 + (cr * 4 + ch) * 256 + off);
    *(float4*)&xs[ch][off] = v;
  }
  __syncthreads();
  int h = t >> 4, w = t & 15;
  float a = b_cr[cr];
  #pragma unroll
  for (int ii = 0; ii < 4; ++ii) {
    const float* wp = w_cr + (cr * 4 + ii) * 9;
    #pragma unroll
    for (int ky = 0; ky < 3; ++ky) {
      int gy = h + ky - 1;
      #pragma unroll
      for (int kx = 0; kx < 3; ++kx) {
        int gx = w + kx - 1;
        float v = (gy >= 0 && gy < 16 && gx >= 0 && gx < 16) ? xs[ii][gy * 16 + gx] : 0.f;
        a += wp[ky * 3 + kx] * v;
      }
    }
  }
  xr[(b * 64 + cr) * 256 + t] = a;
}

// =====================  k1b: gate + dw + multiply -> xc  =====================
// also: wlinT bf16 [16][8192] (transposed), blin bf16 [8192]
__global__ __launch_bounds__(256) void k1b_gate_dw(
    const float* __restrict__ x, const float* __restrict__ xr,
    const float* __restrict__ w_dw3, const float* __restrict__ b_dw3,
    const float* __restrict__ w_dw7, const float* __restrict__ b_dw7,
    const float* __restrict__ w_gate, const float* __restrict__ b_gate,
    const float* __restrict__ bn_gamma, const float* __restrict__ bn_beta,
    const float* __restrict__ bn_mean, const float* __restrict__ bn_var,
    const float* __restrict__ sr_scale, const float* __restrict__ sr_bias,
    const float* __restrict__ w_lin, const float* __restrict__ b_lin,
    short* __restrict__ wlinT, short* __restrict__ blin_bf, short* __restrict__ xc_bf)
{
  __shared__ float xcen[256];
  __shared__ float gs[128];
  int blk = blockIdx.x;
  int b = blk >> 8, h = (blk >> 4) & 15, w = blk & 15;
  int t = threadIdx.x;

  // w_lin -> wlinT bf16 (transposed [i][o])
  {
    int idx = blk * 256 + t;
    wlinT[(idx & 15) * 8192 + (idx >> 4)] = (short)f2bf(w_lin[idx]);
  }
  // b_lin -> bf16 (first 32 blocks)
  if (blk < 32) {
    int idx = blk * 256 + t;
    blin_bf[idx] = (short)f2bf(b_lin[idx]);
  }

  xcen[t] = x[b * 65536 + t * 256 + h * 16 + w];
  __syncthreads();

  int o = t >> 1, half = t & 1;
  {
    const float* wrow = w_gate + o * 256 + half * 128;
    const float* xcn  = xcen + half * 128;
    float ga = 0.f;
    #pragma unroll 8
    for (int ci = 0; ci < 128; ci += 4) {
      float4 wv = *(const float4*)(wrow + ci);
      float4 xv = *(const float4*)(xcn + ci);
      ga += wv.x * xv.x + wv.y * xv.y + wv.z * xv.z + wv.w * xv.w;
    }
    ga += __shfl_xor(ga, 1);
    float inv = bn_gamma[o] * rsqrtf(bn_var[o] + BN_EPS);
    float gg = (ga + b_gate[o] - bn_mean[o]) * inv + bn_beta[o];
    gg = fmaxf(gg, 0.f);
    gg = sr_scale[0] * gg * gg + sr_bias[0];
    if (half == 0) gs[o] = gg;
  }
  __syncthreads();

  if (t < 128) {
    int oc = t;
    float f0;
    if (oc < 64) {
      f0 = b_dw3[oc];
      const float* wp = w_dw3 + oc * 9;
      const float* xp = xr + (b * 64 + oc) * 256;
      #pragma unroll
      for (int ky = 0; ky < 3; ++ky) {
        int gy = h + ky - 1;
        #pragma unroll
        for (int kx = 0; kx < 3; ++kx) {
          int gx = w + kx - 1;
          float v = (gy >= 0 && gy < 16 && gx >= 0 && gx < 16) ? xp[gy * 16 + gx] : 0.f;
          f0 += wp[ky * 3 + kx] * v;
        }
      }
    } else {
      int c5 = oc - 64;
      f0 = b_dw7[c5];
      const float* wp = w_dw7 + c5 * 25;
      const float* xp = xr + (b * 64 + c5) * 256;
      #pragma unroll
      for (int ky = 0; ky < 5; ++ky) {
        int gy = h + ky - 2;
        #pragma unroll
        for (int kx = 0; kx < 5; ++kx) {
          int gx = w + kx - 2;
          float v = (gy >= 0 && gy < 16 && gx >= 0 && gx < 16) ? xp[gy * 16 + gx] : 0.f;
          f0 += wp[ky * 5 + kx] * v;
        }
      }
    }
    int pix = (b * 16 + h) * 16 + w;
    xc_bf[pix * 128 + oc] = (short)f2bf(f0 * gs[oc]);
  }
}

// =====================  k2: fused T-space dynamic conv  =====================
// 1024 blocks x 256 thr (4 waves). Block = half patch (32 pix).
// Wave (pt = w&1, jh = w>>1): pixels [pt*16,pt*16+16), j in [jh*16, jh*16+16).
// LDS: Ylds 16 KB + scratch 16 KB (staging, then per-wave T/U). 4 blocks/CU.
__global__ __launch_bounds__(256, 4) void k2_fused(
    const float* __restrict__ y, const short* __restrict__ wlinT,
    const short* __restrict__ blin, const short* __restrict__ xc_bf,
    float* __restrict__ out)
{
  __shared__ __align__(16) short Ylds[8192];    // [32 pix][256 c] bf16, swizzled
  __shared__ __align__(16) float scratch[4096]; // staging; then T/U per wave

  // XCD-aware decode (as R5): twins of a patch share an XCD.
  int phys = blockIdx.x;
  int x_ = phys & 7, q_ = phys >> 3;
  int sub = q_ & 3, pphi = q_ >> 2;
  int pp = pphi * 8 + x_;
  int b = pp >> 7, f = (pp >> 3) & 15, gp = pp & 7;
  int g = gp * 2 + (sub & 1);
  int half = sub >> 1;

  int tid = threadIdx.x;
  int wave = tid >> 6, lane = tid & 63;
  int quad = lane >> 4, l16 = lane & 15;
  int pt = wave & 1, jh = wave >> 1;
  int npix = (b * 16 + f) * 16 + g;

  const float* yb = y + b * 4194304 + (f * 8 + half * 4) * 128 + g * 8;

  // ---- stage Y half-patch: 2 passes of 128 channels ----
  for (int pass = 0; pass < 2; ++pass) {
    #pragma unroll
    for (int it = 0; it < 4; ++it) {
      int task = it * 256 + tid;              // 128c x 8 pixel-float4
      int c = task >> 3, pf = task & 7;
      *(float4*)&scratch[c * 32 + pf * 4] =
          *(const float4*)(yb + (pass * 128 + c) * 16384 + (pf >> 1) * 128 + (pf & 1) * 4);
    }
    __syncthreads();
    #pragma unroll
    for (int it = 0; it < 2; ++it) {
      int task = it * 256 + tid;
      int pix = task & 31, cg = task >> 5;    // 32 pix x 16 c-groups of 8
      float s0 = scratch[(cg * 8 + 0) * 32 + pix];
      float s1 = scratch[(cg * 8 + 1) * 32 + pix];
      float s2 = scratch[(cg * 8 + 2) * 32 + pix];
      float s3 = scratch[(cg * 8 + 3) * 32 + pix];
      float s4 = scratch[(cg * 8 + 4) * 32 + pix];
      float s5 = scratch[(cg * 8 + 5) * 32 + pix];
      float s6 = scratch[(cg * 8 + 6) * 32 + pix];
      float s7 = scratch[(cg * 8 + 7) * 32 + pix];
      uint4 pk;
      pk.x = pk2bf(s0, s1); pk.y = pk2bf(s2, s3);
      pk.z = pk2bf(s4, s5); pk.w = pk2bf(s6, s7);
      int chunk = pass * 16 + cg;
      int ph = chunk ^ (pix & 7);
      *(uint4*)&Ylds[pix * 256 + ph * 8] = pk;
    }
    __syncthreads();
  }

  // ---- hoist Y B-fragments for this wave's 16 pixels: 32 VGPRs ----
  short8 Bh[8];
  int nn = pt * 16 + l16;
  #pragma unroll
  for (int kc = 0; kc < 8; ++kc) {
    int chunk = kc * 4 + quad;
    int ph = chunk ^ (nn & 7);
    Bh[kc] = *(const short8*)&Ylds[nn * 256 + ph * 8];
  }

  // per-wave scratch: T double-buffer (2x256 shorts) + U (256 shorts)
  short* tw = (short*)scratch + wave * 1024;
  f32x4 zero4 = {0.f, 0.f, 0.f, 0.f};

  // ---- U[j,p] = sum_c b_lin[j*256+c] * Y[c,p]  (this wave's 16 j,16 p) ----
  {
    f32x4 du = zero4;
    #pragma unroll
    for (int kc = 0; kc < 8; ++kc) {
      short8 ab = *(const short8*)(blin + (jh * 16 + l16) * 256 + kc * 32 + quad * 8);
      du = __builtin_amdgcn_mfma_f32_16x16x32_bf16(ab, Bh[kc], du, 0, 0, 0);
    }
    // D row = j-local (quad*4+r), col = p (l16) -> store U^T[p][jl]
    uint2 pk; pk.x = pk2bf(du[0], du[1]); pk.y = pk2bf(du[2], du[3]);
    *(uint2*)&tw[512 + l16 * 16 + quad * 4] = pk;
  }

  // ---- A2 (second GEMM): A[m=g][k]: k<16 = xc[g,k], k=16 -> 1.0 ----
  short8 a2 = {0, 0, 0, 0, 0, 0, 0, 0};
  if (quad < 2) {
    if (l16 < 8) a2 = *(const short8*)(xc_bf + npix * 128 + l16 * 16 + quad * 8);
  } else if (quad == 2) {
    a2[0] = (short)0x3F80;                    // 1.0 bf16
  }

  // ---- j-loop: T_j = wlinT_j @ Y ; out rows e=g*32+j = xc @ T_j + U_j ----
  float* ob = out + b * 4194304 + (f * 8 + half * 4) * 128 + g * 8;
  int pix = pt * 16 + l16;
  float* oa = ob + (pix >> 3) * 128 + (pix & 7);

  #pragma unroll 2
  for (int j = 0; j < 16; ++j) {
    int jg = jh * 16 + j;
    const short* ap = wlinT + l16 * 8192 + jg * 256 + quad * 8;
    f32x4 d = zero4;
    #pragma unroll
    for (int kc = 0; kc < 8; ++kc) {
      short8 af = *(const short8*)(ap + kc * 32);
      d = __builtin_amdgcn_mfma_f32_16x16x32_bf16(af, Bh[kc], d, 0, 0, 0);
    }
    // write T^T[p][i] bf16 (D: row i = quad*4+r, col p = l16), dbuf by j&1
    short* tb = tw + (j & 1) * 256;
    {
      uint2 pk; pk.x = pk2bf(d[0], d[1]); pk.y = pk2bf(d[2], d[3]);
      *(uint2*)&tb[l16 * 16 + quad * 4] = pk;
    }
    // B2[k][p]: k<16 = T_j[k][p]; k=16 = U[j][p]; else 0
    short8 b2 = {0, 0, 0, 0, 0, 0, 0, 0};
    if (quad < 2) {
      b2 = *(const short8*)&tb[l16 * 16 + quad * 8];
    } else if (quad == 2) {
      b2[0] = tw[512 + l16 * 16 + j];
    }
    f32x4 d2 = __builtin_amdgcn_mfma_f32_16x16x32_bf16(a2, b2, zero4, 0, 0, 0);
    // D2 row = g (quad*4+r, valid g<8 -> quads 0,1), col = p
    if (quad < 2) {
      #pragma unroll
      for (int r = 0; r < 4; ++r)
        oa[(size_t)((quad * 4 + r) * 32 + jg) * 16384] = d2[r];
    }
  }
}

// ============================  launcher  ============================
extern "C" void kernel_launch(void* const* d_in, const int* in_sizes, int n_in,
                              void* d_out, int out_size, void* d_ws, size_t ws_size,
                              hipStream_t stream) {
  const float* x        = (const float*)d_in[0];
  const float* y        = (const float*)d_in[1];
  const float* w_cr     = (const float*)d_in[2];
  const float* b_cr     = (const float*)d_in[3];
  const float* w_dw3    = (const float*)d_in[4];
  const float* b_dw3    = (const float*)d_in[5];
  const float* w_dw7    = (const float*)d_in[6];
  const float* b_dw7    = (const float*)d_in[7];
  const float* w_gate   = (const float*)d_in[8];
  const float* b_gate   = (const float*)d_in[9];
  const float* bn_gamma = (const float*)d_in[10];
  const float* bn_beta  = (const float*)d_in[11];
  const float* bn_mean  = (const float*)d_in[12];
  const float* bn_var   = (const float*)d_in[13];
  const float* sr_scale = (const float*)d_in[14];
  const float* sr_bias  = (const float*)d_in[15];
  const float* w_lin    = (const float*)d_in[16];
  const float* b_lin    = (const float*)d_in[17];
  float* out = (float*)d_out;

  // ws: xc_bf 128KB | wlinT 256KB | blin 16KB | xr 128KB   (no Wd!)
  short* xc_bf   = (short*)d_ws;
  short* wlinT   = (short*)((char*)d_ws + 131072);
  short* blin_bf = (short*)((char*)d_ws + 131072 + 262144);
  float* xr      = (float*)((char*)d_ws + 131072 + 262144 + 16384);

  hipLaunchKernelGGL(k1a_groupconv, dim3(128), dim3(256), 0, stream, x, w_cr, b_cr, xr);
  hipLaunchKernelGGL(k1b_gate_dw, dim3(512), dim3(256), 0, stream,
                     x, xr, w_dw3, b_dw3, w_dw7, b_dw7, w_gate, b_gate,
                     bn_gamma, bn_beta, bn_mean, bn_var, sr_scale, sr_bias,
                     w_lin, b_lin, wlinT, blin_bf, xc_bf);
  hipLaunchKernelGGL(k2_fused, dim3(1024), dim3(256), 0, stream,
                     y, wlinT, blin_bf, xc_bf, out);
}